// Round 2
// baseline (363.059 us; speedup 1.0000x reference)
//
#include <hip/hip_runtime.h>
#include <math.h>

#define WSZ 8
#define NT 16
#define NR 8
#define PD 32
#define HG 48
#define WG 48
#define NB 8
#define CH 96
#define HW 384
#define XHW (HW * HW)
#define S8 0.70710678118654752f

static __device__ const float CT16[16] = {
    1.0f, 0.9238795325112867f, 0.7071067811865476f, 0.3826834323650898f,
    0.0f, -0.3826834323650898f, -0.7071067811865476f, -0.9238795325112867f,
    -1.0f, -0.9238795325112867f, -0.7071067811865476f, -0.3826834323650898f,
    0.0f, 0.3826834323650898f, 0.7071067811865476f, 0.9238795325112867f};
static __device__ const float ST16[16] = {
    0.0f, 0.3826834323650898f, 0.7071067811865476f, 0.9238795325112867f,
    1.0f, 0.9238795325112867f, 0.7071067811865476f, 0.3826834323650898f,
    0.0f, -0.3826834323650898f, -0.7071067811865476f, -0.9238795325112867f,
    -1.0f, -0.9238795325112867f, -0.7071067811865476f, -0.3826834323650898f};

#define MAGR(x_) log1pf(0.125f * fabsf(x_))
#define MAGC(re_, im_) log1pf(0.125f * sqrtf((re_) * (re_) + (im_) * (im_)))

// Setup: Wt[c][o] = W[o][c] into ws[0..3071]; polar tables into
// ws[3072..3583] (int idx x4 per entry) and ws[3584..4095] (weights).
__global__ void lpp_setup(const float* __restrict__ Wp, float* __restrict__ ws) {
  int t = blockIdx.x * 256 + threadIdx.x;
  if (t < CH * PD) {
    int o = t & 31, c = t >> 5;
    ws[c * 32 + o] = Wp[o * CH + c];
  }
  if (t < 128) {
    int r = t >> 4, tt = t & 15;
    float rad = (float)r / 7.0f;
    float px = (rad * CT16[tt] + 1.0f) * 3.5f;
    float py = (rad * ST16[tt] + 1.0f) * 3.5f;
    float xf = floorf(px), yf = floorf(py);
    float wx = px - xf, wy = py - yf;
    int ix = (int)xf, iy = (int)yf;
    int xi0 = min(max(ix, 0), 7), xi1 = min(max(ix + 1, 0), 7);
    int yi0 = min(max(iy, 0), 7), yi1 = min(max(iy + 1, 0), 7);
    bool vx0 = (ix >= 0) && (ix < 8), vx1 = (ix + 1 >= 0) && (ix + 1 < 8);
    bool vy0 = (iy >= 0) && (iy < 8), vy1 = (iy + 1 >= 0) && (iy + 1 < 8);
    int* wsi = (int*)ws;
    wsi[3072 + 4 * t + 0] = yi0 * 8 + xi0;
    wsi[3072 + 4 * t + 1] = yi0 * 8 + xi1;
    wsi[3072 + 4 * t + 2] = yi1 * 8 + xi0;
    wsi[3072 + 4 * t + 3] = yi1 * 8 + xi1;
    ws[3584 + 4 * t + 0] = (vx0 && vy0) ? (1.f - wx) * (1.f - wy) : 0.f;
    ws[3584 + 4 * t + 1] = (vx1 && vy0) ? wx * (1.f - wy) : 0.f;
    ws[3584 + 4 * t + 2] = (vx0 && vy1) ? (1.f - wx) * wy : 0.f;
    ws[3584 + 4 * t + 3] = (vx1 && vy1) ? wx * wy : 0.f;
  }
}

__global__ __launch_bounds__(256, 2) void lpp_main(
    const float* __restrict__ x, const float* __restrict__ bp,
    const float* __restrict__ ws, float* __restrict__ out) {
  __shared__ float planes[256 * 64];  // 64KB: swizzled feat/mag planes
  __shared__ float obuf[144];

  const int tid = threadIdx.x;
  const int gid = blockIdx.x;
  const int wxg = gid % 6;
  const int hy = (gid / 6) % HG;
  const int b = gid / (6 * HG);

  // thread owns pixels (krow, colp) and (krow, colp+1) of the 8x64 strip
  const int krow = tid >> 5;
  const int colp = (tid & 31) << 1;

  const float* xb = x + (size_t)b * CH * XHW + (size_t)(hy * 8 + krow) * HW +
                    wxg * 64 + colp;

  float acc0[32], acc1[32];
#pragma unroll
  for (int o = 0; o < 32; ++o) { acc0[o] = 0.f; acc1[o] = 0.f; }

  float2 xA[8], xB[8];
#pragma unroll
  for (int j = 0; j < 8; ++j)
    xA[j] = *(const float2*)(xb + (size_t)j * XHW);

  // ---- projection: global->reg x, SGPR weights, zero LDS ----
#define FMA_BLOCK(CUR, NXT, CBASE, PREF, NBASE)                             \
  {                                                                         \
    if (PREF) {                                                             \
      _Pragma("unroll") for (int j = 0; j < 8; ++j)                         \
          NXT[j] = *(const float2*)(xb + (size_t)((NBASE) + j) * XHW);      \
    }                                                                       \
    _Pragma("unroll") for (int j = 0; j < 8; ++j) {                         \
      const float4* w4 = (const float4*)(ws + ((CBASE) + j) * 32);          \
      float2 xv = CUR[j];                                                   \
      _Pragma("unroll") for (int o4 = 0; o4 < 8; ++o4) {                    \
        float4 w = w4[o4];                                                  \
        acc0[o4 * 4 + 0] = fmaf(w.x, xv.x, acc0[o4 * 4 + 0]);               \
        acc0[o4 * 4 + 1] = fmaf(w.y, xv.x, acc0[o4 * 4 + 1]);               \
        acc0[o4 * 4 + 2] = fmaf(w.z, xv.x, acc0[o4 * 4 + 2]);               \
        acc0[o4 * 4 + 3] = fmaf(w.w, xv.x, acc0[o4 * 4 + 3]);               \
        acc1[o4 * 4 + 0] = fmaf(w.x, xv.y, acc1[o4 * 4 + 0]);               \
        acc1[o4 * 4 + 1] = fmaf(w.y, xv.y, acc1[o4 * 4 + 1]);               \
        acc1[o4 * 4 + 2] = fmaf(w.z, xv.y, acc1[o4 * 4 + 2]);               \
        acc1[o4 * 4 + 3] = fmaf(w.w, xv.y, acc1[o4 * 4 + 3]);               \
      }                                                                     \
    }                                                                       \
  }

  for (int cb = 0; cb < 12; cb += 2) {
    FMA_BLOCK(xA, xB, cb * 8, 1, (cb + 1) * 8)
    FMA_BLOCK(xB, xA, (cb + 1) * 8, (cb + 2) < 12, (cb + 2) * 8)
  }

#pragma unroll
  for (int o = 0; o < 32; ++o) {
    float bo = bp[o];
    acc0[o] += bo;
    acc1[o] += bo;
  }

  // ---- scatter feat to swizzled planes (ds_write_b64, conflict-optimal) ----
  // swizzle: value for offset m of plane p lives at m ^ s(p),
  // s(p) = (p&31) ^ ((p>>5)<<2)
  {
    const int win = colp >> 3;
    const int off0 = krow * 8 + (colp & 7);  // even
    const int sw = win << 2;
#pragma unroll
    for (int o = 0; o < 32; ++o) {
      int p = win * 32 + o;
      int s = o ^ sw;
      int base = p * 64 + ((off0 ^ s) & ~1);
      float2 wv;
      if (o & 1) { wv.x = acc1[o]; wv.y = acc0[o]; }
      else       { wv.x = acc0[o]; wv.y = acc1[o]; }
      *(float2*)&planes[base] = wv;
    }
  }
  __syncthreads();

  // ---- per-thread 8x8 real FFT -> shifted log-magnitude (own plane) ----
  const int svb = (tid & 31) ^ ((tid >> 5) << 2);
  const int vb = (tid * 64) ^ svb;
  float rr[8][8];
#pragma unroll
  for (int k = 0; k < 8; ++k) {
    float v[8];
#pragma unroll
    for (int j = 0; j < 8; ++j) v[j] = planes[vb ^ (k * 8 + j)];
    float a0 = v[0] + v[4], a1 = v[0] - v[4], a2 = v[2] + v[6], a3 = v[2] - v[6];
    float b0 = v[1] + v[5], b1 = v[1] - v[5], b2 = v[3] + v[7], b3 = v[3] - v[7];
    float e0 = a0 + a2, e2 = a0 - a2, o0 = b0 + b2, o2 = b0 - b2;
    float t1 = S8 * (b1 - b3), t2 = S8 * (b1 + b3);
    rr[k][0] = e0 + o0; rr[k][1] = e0 - o0;
    rr[k][2] = a1 + t1; rr[k][3] = -a3 - t2;
    rr[k][4] = e2;      rr[k][5] = -o2;
    rr[k][6] = a1 - t1; rr[k][7] = a3 - t2;
  }
  float mg0[5], mg4[5], mg1[8], mg2[8], mg3[8];
#define REALCOL(SLOT, OUT)                                                    \
  {                                                                           \
    float a0 = rr[0][SLOT] + rr[4][SLOT], a1 = rr[0][SLOT] - rr[4][SLOT];     \
    float a2 = rr[2][SLOT] + rr[6][SLOT], a3 = rr[2][SLOT] - rr[6][SLOT];     \
    float b0 = rr[1][SLOT] + rr[5][SLOT], b1 = rr[1][SLOT] - rr[5][SLOT];     \
    float b2 = rr[3][SLOT] + rr[7][SLOT], b3 = rr[3][SLOT] - rr[7][SLOT];     \
    float e0 = a0 + a2, e2 = a0 - a2, o0 = b0 + b2, o2 = b0 - b2;             \
    float t1 = S8 * (b1 - b3), t2 = S8 * (b1 + b3);                           \
    OUT[0] = MAGR(e0 + o0); OUT[4] = MAGR(e0 - o0);                           \
    OUT[1] = MAGC(a1 + t1, -a3 - t2);                                         \
    OUT[2] = MAGC(e2, -o2);                                                   \
    OUT[3] = MAGC(a1 - t1, a3 - t2);                                          \
  }
#define CPLXCOL(SR, SI, OUT)                                                  \
  {                                                                           \
    float t0r = rr[0][SR] + rr[4][SR], t0i = rr[0][SI] + rr[4][SI];           \
    float t1r = rr[0][SR] - rr[4][SR], t1i = rr[0][SI] - rr[4][SI];           \
    float t2r = rr[2][SR] + rr[6][SR], t2i = rr[2][SI] + rr[6][SI];           \
    float t3r = rr[2][SR] - rr[6][SR], t3i = rr[2][SI] - rr[6][SI];           \
    float E0r = t0r + t2r, E0i = t0i + t2i, E2r = t0r - t2r, E2i = t0i - t2i; \
    float E1r = t1r + t3i, E1i = t1i - t3r, E3r = t1r - t3i, E3i = t1i + t3r; \
    float u0r = rr[1][SR] + rr[5][SR], u0i = rr[1][SI] + rr[5][SI];           \
    float u1r = rr[1][SR] - rr[5][SR], u1i = rr[1][SI] - rr[5][SI];           \
    float u2r = rr[3][SR] + rr[7][SR], u2i = rr[3][SI] + rr[7][SI];           \
    float u3r = rr[3][SR] - rr[7][SR], u3i = rr[3][SI] - rr[7][SI];           \
    float O0r = u0r + u2r, O0i = u0i + u2i, O2r = u0r - u2r, O2i = u0i - u2i; \
    float O1r = u1r + u3i, O1i = u1i - u3r, O3r = u1r - u3i, O3i = u1i + u3r; \
    float W1r = S8 * (O1r + O1i), W1i = S8 * (O1i - O1r);                     \
    float W2r = O2i, W2i = -O2r;                                              \
    float W3r = S8 * (O3i - O3r), W3i = -S8 * (O3r + O3i);                    \
    OUT[0] = MAGC(E0r + O0r, E0i + O0i); OUT[4] = MAGC(E0r - O0r, E0i - O0i); \
    OUT[1] = MAGC(E1r + W1r, E1i + W1i); OUT[5] = MAGC(E1r - W1r, E1i - W1i); \
    OUT[2] = MAGC(E2r + W2r, E2i + W2i); OUT[6] = MAGC(E2r - W2r, E2i - W2i); \
    OUT[3] = MAGC(E3r + W3r, E3i + W3i); OUT[7] = MAGC(E3r - W3r, E3i - W3i); \
  }
  REALCOL(0, mg0)
  REALCOL(1, mg4)
  CPLXCOL(2, 3, mg1)
  CPLXCOL(4, 5, mg2)
  CPLXCOL(6, 7, mg3)
#pragma unroll
  for (int up = 0; up < 8; ++up) {
#pragma unroll
    for (int vp = 0; vp < 8; ++vp) {
      const int u = (up + 4) & 7, v = (vp + 4) & 7;
      float m;
      if (v == 0)      m = mg0[(u <= 4) ? u : (8 - u)];
      else if (v == 4) m = mg4[(u <= 4) ? u : (8 - u)];
      else if (v == 1) m = mg1[u];
      else if (v == 2) m = mg2[u];
      else if (v == 3) m = mg3[u];
      else { const int uu = (8 - u) & 7;
             m = (v == 5) ? mg3[uu] : (v == 6) ? mg2[uu] : mg1[uu]; }
      planes[vb ^ (up * 8 + vp)] = m;
    }
  }

  // ---- polar bilinear gather (tables via scalar loads from ws) ----
  const int* tI = (const int*)ws + 3072;
  const float* tW = ws + 3584;
  float psum[16];
#pragma unroll
  for (int t = 0; t < 16; ++t) psum[t] = 0.f;
  for (int r = 0; r < 8; ++r) {
#pragma unroll
    for (int t = 0; t < 16; ++t) {
      int e4 = (r * 16 + t) * 4;
      int i0 = tI[e4 + 0], i1 = tI[e4 + 1], i2 = tI[e4 + 2], i3 = tI[e4 + 3];
      float w0 = tW[e4 + 0], w1 = tW[e4 + 1], w2 = tW[e4 + 2], w3 = tW[e4 + 3];
      psum[t] += w0 * planes[vb ^ i0] + w1 * planes[vb ^ i1] +
                 w2 * planes[vb ^ i2] + w3 * planes[vb ^ i3];
    }
  }

  // ---- reduce over 32 channels ----
#pragma unroll
  for (int m = 1; m < 32; m <<= 1)
#pragma unroll
    for (int t = 0; t < 16; ++t) psum[t] += __shfl_xor(psum[t], m, 64);

  // ---- softmax + entropy ----
  float lmax = psum[0];
#pragma unroll
  for (int t = 1; t < 16; ++t) lmax = fmaxf(lmax, psum[t]);
  float ev[16], ssum = 0.f;
#pragma unroll
  for (int t = 0; t < 16; ++t) {
    ev[t] = expf((psum[t] - lmax) * (1.0f / 256.0f));
    ssum += ev[t];
  }
  float inv = 1.0f / ssum;
  float H = 0.f;
#pragma unroll
  for (int t = 0; t < 16; ++t) {
    float d = ev[t] * inv;
    H -= d * logf(fmaxf(d, 1e-8f));
  }
  float conf = 1.0f - H * (1.0f / 2.7725887222397811f);
  conf = fminf(fmaxf(conf, 0.f), 1.f);

  // ---- stage + coalesced store ----
  {
    int l32 = tid & 31, w8 = tid >> 5;
    if (l32 < 16) {
      float dv = ev[0];
#pragma unroll
      for (int t = 1; t < 16; ++t) dv = (l32 == t) ? ev[t] : dv;
      obuf[w8 * 16 + l32] = dv * inv;
    }
    if (l32 == 16) obuf[128 + w8] = conf;
  }
  __syncthreads();

  if (tid < 128) {
    int t = tid >> 3, win = tid & 7;
    int wx = wxg * 8 + win;
    out[((size_t)(b * NT + t) * HG + hy) * WG + wx] = obuf[win * 16 + t];
  } else if (tid < 136) {
    int win = tid - 128;
    int wx = wxg * 8 + win;
    out[(size_t)NB * NT * HG * WG + ((size_t)b * HG + hy) * WG + wx] =
        obuf[128 + win];
  }
}

extern "C" void kernel_launch(void* const* d_in, const int* in_sizes, int n_in,
                              void* d_out, int out_size, void* d_ws,
                              size_t ws_size, hipStream_t stream) {
  (void)in_sizes; (void)n_in; (void)ws_size; (void)out_size;
  const float* x = (const float*)d_in[0];
  const float* Wp = (const float*)d_in[1];
  const float* bp = (const float*)d_in[2];
  float* ws = (float*)d_ws;
  float* out = (float*)d_out;
  lpp_setup<<<12, 256, 0, stream>>>(Wp, ws);
  lpp_main<<<NB * HG * 6, 256, 0, stream>>>(x, bp, ws, out);
}

// Round 3
// 135.362 us; speedup vs baseline: 2.6821x; 2.6821x over previous
//
#include <hip/hip_runtime.h>
#include <hip/hip_bf16.h>
#include <math.h>

#define NT 16
#define NR 8
#define PD 32
#define HG 48
#define WG 48
#define NB 8
#define CH 96
#define HW 384
#define XHW (HW * HW)
#define S8 0.70710678118654752f

typedef short short8 __attribute__((ext_vector_type(8)));
typedef float f32x4 __attribute__((ext_vector_type(4)));

static __device__ const float CT16[16] = {
    1.0f, 0.9238795325112867f, 0.7071067811865476f, 0.3826834323650898f,
    0.0f, -0.3826834323650898f, -0.7071067811865476f, -0.9238795325112867f,
    -1.0f, -0.9238795325112867f, -0.7071067811865476f, -0.3826834323650898f,
    0.0f, 0.3826834323650898f, 0.7071067811865476f, 0.9238795325112867f};
static __device__ const float ST16[16] = {
    0.0f, 0.3826834323650898f, 0.7071067811865476f, 0.9238795325112867f,
    1.0f, 0.9238795325112867f, 0.7071067811865476f, 0.3826834323650898f,
    0.0f, -0.3826834323650898f, -0.7071067811865476f, -0.9238795325112867f,
    -1.0f, -0.9238795325112867f, -0.7071067811865476f, -0.3826834323650898f};

static __device__ __forceinline__ unsigned short f2bf(float f) {
  unsigned int u = __float_as_uint(f);
  u = u + 0x7fffu + ((u >> 16) & 1u);
  return (unsigned short)(u >> 16);
}
static __device__ __forceinline__ unsigned int pk2bf(float a, float b) {
  union { __hip_bfloat162 h; unsigned int u; } c;
  c.h = __float22bfloat162_rn(make_float2(a, b));
  return c.u;
}
static __device__ __forceinline__ float bf2f_lo(unsigned int v) {
  return __uint_as_float(v << 16);
}
static __device__ __forceinline__ float bf2f_hi(unsigned int v) {
  return __uint_as_float(v & 0xffff0000u);
}

#define MAGR(x_) log1pf(0.125f * fabsf(x_))
#define MAGC(re_, im_) log1pf(0.125f * sqrtf((re_) * (re_) + (im_) * (im_)))

// ws layout (ushort units): [0..3071] W B-fragments (6 frags x 64 lanes x 8),
// [3072..4095] G B-fragments (2 frags x 64 lanes x 8).
__global__ void lpp_setup(const float* __restrict__ Wp,
                          unsigned short* __restrict__ ws) {
  int gt = blockIdx.x * 256 + threadIdx.x;
  if (gt < 384) {  // W fragments: B[k][n] = W[n*96+k], bf16
    int f = gt >> 6, l = gt & 63;
    int ks = f >> 1, nt = f & 1;
    int n = nt * 16 + (l & 15);
    int kbase = ks * 32 + (l >> 4) * 8;
    for (int jj = 0; jj < 8; ++jj)
      ws[(f * 64 + l) * 8 + jj] = f2bf(Wp[n * CH + kbase + jj]);
  }
  if (gt >= 1024 && gt < 2048) {  // dense polar matrix G[j][t]
    int q = gt - 1024;
    int j = q >> 4, t = q & 15;
    float g = 0.f;
    for (int r = 0; r < 8; ++r) {
      float rad = (float)r / 7.0f;
      float px = (rad * CT16[t] + 1.0f) * 3.5f;
      float py = (rad * ST16[t] + 1.0f) * 3.5f;
      float xf = floorf(px), yf = floorf(py);
      float wx = px - xf, wy = py - yf;
      int ix = (int)xf, iy = (int)yf;
      int xi0 = min(max(ix, 0), 7), xi1 = min(max(ix + 1, 0), 7);
      int yi0 = min(max(iy, 0), 7), yi1 = min(max(iy + 1, 0), 7);
      bool vx0 = (ix >= 0) && (ix < 8), vx1 = (ix + 1 >= 0) && (ix + 1 < 8);
      bool vy0 = (iy >= 0) && (iy < 8), vy1 = (iy + 1 >= 0) && (iy + 1 < 8);
      float w0 = (vx0 && vy0) ? (1.f - wx) * (1.f - wy) : 0.f;
      float w1 = (vx1 && vy0) ? wx * (1.f - wy) : 0.f;
      float w2 = (vx0 && vy1) ? (1.f - wx) * wy : 0.f;
      float w3 = (vx1 && vy1) ? wx * wy : 0.f;
      if (yi0 * 8 + xi0 == j) g += w0;
      if (yi0 * 8 + xi1 == j) g += w1;
      if (yi1 * 8 + xi0 == j) g += w2;
      if (yi1 * 8 + xi1 == j) g += w3;
    }
    int f = j >> 5, kc = (j >> 3) & 3, jj = j & 7;
    int l = (kc << 4) | t;
    ws[3072 + (f * 64 + l) * 8 + jj] = f2bf(g);
  }
}

__global__ __launch_bounds__(256, 4) void lpp_main(
    const float* __restrict__ x, const float* __restrict__ bp,
    const unsigned short* __restrict__ ws, float* __restrict__ out) {
  // 32KB, triple-purpose: x A-staging -> feat planes -> mag A-fragments
  __shared__ short8 ldsX[2048];
  __shared__ float obuf[144];
  unsigned int* ldsU = (unsigned int*)ldsX;

  const int tid = threadIdx.x;
  const int lane = tid & 63;
  const int wave = tid >> 6;
  const int gid = blockIdx.x;
  const int wxg = gid % 6;
  const int hy = (gid / 6) % HG;
  const int b = gid / (6 * HG);
  const short8* wsV = (const short8*)ws;

  f32x4 acc[8][2];
#pragma unroll
  for (int m = 0; m < 8; ++m) {
    acc[m][0] = (f32x4){0.f, 0.f, 0.f, 0.f};
    acc[m][1] = (f32x4){0.f, 0.f, 0.f, 0.f};
  }

  const size_t xcb = (size_t)b * CH * XHW;
  const int kcA = lane >> 4;  // A-fragment k-chunk
  // ---- projection: 3 K-chunks of 32 ch, staged fp32->bf16 into LDS ----
  for (int ks = 0; ks < 3; ++ks) {
    if (ks) __syncthreads();  // prior MFMA done with ldsX
#pragma unroll
    for (int g2 = 0; g2 < 2; ++g2) {
      int id = tid + 256 * g2;
      int kc = id >> 7;
      int p0 = (id & 127) << 2;           // 4-aligned pixel base
      int row = (p0 >> 3) & 7;
      int gcol = wxg * 64 + ((p0 >> 6) << 3) + (p0 & 7);
      const float* xp = x + xcb + (size_t)(ks * 32 + kc * 8) * XHW +
                        (size_t)(hy * 8 + row) * HW + gcol;
      float q[8][4];
#pragma unroll
      for (int jj = 0; jj < 8; ++jj) {
        float4 v = *(const float4*)(xp + (size_t)jj * XHW);
        q[jj][0] = v.x; q[jj][1] = v.y; q[jj][2] = v.z; q[jj][3] = v.w;
      }
      int z = (p0 >> 3) & 7;
      int base3 = kc * 512 + (p0 & ~7);
#pragma unroll
      for (int i = 0; i < 4; ++i) {
        union { unsigned int u[4]; short8 v; } pk;
#pragma unroll
        for (int k2 = 0; k2 < 4; ++k2)
          pk.u[k2] = pk2bf(q[2 * k2][i], q[2 * k2 + 1][i]);
        int u = base3 | ((((p0 & 4) | i)) ^ z);
        ldsX[u] = pk.v;
      }
    }
    __syncthreads();
    short8 b0 = wsV[(ks * 2 + 0) * 64 + lane];
    short8 b1 = wsV[(ks * 2 + 1) * 64 + lane];
    int prow = wave * 128 + (lane & 15);
#pragma unroll
    for (int m = 0; m < 8; ++m) {
      int p = prow + m * 16;
      int s = kcA * 512 + p;
      short8 a = ldsX[s ^ ((p >> 3) & 7)];
      acc[m][0] = __builtin_amdgcn_mfma_f32_16x16x32_bf16(a, b0, acc[m][0], 0, 0, 0);
      acc[m][1] = __builtin_amdgcn_mfma_f32_16x16x32_bf16(a, b1, acc[m][1], 0, 0, 0);
    }
  }
  __syncthreads();

  // ---- scatter feat (C layout: col=lane&15, row=4*(lane>>4)+reg) ----
  {
    const float bias0 = bp[lane & 15];
    const float bias1 = bp[16 + (lane & 15)];
    int jb = (lane >> 4) << 2;
#pragma unroll
    for (int m = 0; m < 8; ++m) {
      int win = 2 * wave + (m >> 2);
      int j0 = ((m & 3) << 4) + jb;
#pragma unroll
      for (int nt = 0; nt < 2; ++nt) {
        int p = win * 32 + nt * 16 + (lane & 15);
        float bs = nt ? bias1 : bias0;
        int sh = (p & 15) << 1;
        int dwb = p * 32;
        unsigned int w0 = pk2bf(acc[m][nt][0] + bs, acc[m][nt][1] + bs);
        unsigned int w1 = pk2bf(acc[m][nt][2] + bs, acc[m][nt][3] + bs);
        ldsU[dwb + ((j0 >> 1) ^ sh)] = w0;
        ldsU[dwb + (((j0 >> 1) + 1) ^ sh)] = w1;
      }
    }
  }
  __syncthreads();

  // ---- per-thread 8x8 real FFT -> shifted log-magnitude ----
  {
    const int p = tid;
    const int sh = (p & 15) << 1;
    const int dwb = p * 32;
    float rr[8][8];
#pragma unroll
    for (int k = 0; k < 8; ++k) {
      float v[8];
#pragma unroll
      for (int i = 0; i < 4; ++i) {
        unsigned int u = ldsU[dwb + ((k * 4 + i) ^ sh)];
        v[2 * i] = bf2f_lo(u);
        v[2 * i + 1] = bf2f_hi(u);
      }
      float a0 = v[0] + v[4], a1 = v[0] - v[4], a2 = v[2] + v[6], a3 = v[2] - v[6];
      float b0 = v[1] + v[5], b1 = v[1] - v[5], b2 = v[3] + v[7], b3 = v[3] - v[7];
      float e0 = a0 + a2, e2 = a0 - a2, o0 = b0 + b2, o2 = b0 - b2;
      float t1 = S8 * (b1 - b3), t2 = S8 * (b1 + b3);
      rr[k][0] = e0 + o0; rr[k][1] = e0 - o0;
      rr[k][2] = a1 + t1; rr[k][3] = -a3 - t2;
      rr[k][4] = e2;      rr[k][5] = -o2;
      rr[k][6] = a1 - t1; rr[k][7] = a3 - t2;
    }
    float mg0[5], mg4[5], mg1[8], mg2[8], mg3[8];
#define REALCOL(SLOT, OUT)                                                    \
  {                                                                           \
    float a0 = rr[0][SLOT] + rr[4][SLOT], a1 = rr[0][SLOT] - rr[4][SLOT];     \
    float a2 = rr[2][SLOT] + rr[6][SLOT], a3 = rr[2][SLOT] - rr[6][SLOT];     \
    float b0 = rr[1][SLOT] + rr[5][SLOT], b1 = rr[1][SLOT] - rr[5][SLOT];     \
    float b2 = rr[3][SLOT] + rr[7][SLOT], b3 = rr[3][SLOT] - rr[7][SLOT];     \
    float e0 = a0 + a2, e2 = a0 - a2, o0 = b0 + b2, o2 = b0 - b2;             \
    float t1 = S8 * (b1 - b3), t2 = S8 * (b1 + b3);                           \
    OUT[0] = MAGR(e0 + o0); OUT[4] = MAGR(e0 - o0);                           \
    OUT[1] = MAGC(a1 + t1, -a3 - t2);                                         \
    OUT[2] = MAGC(e2, -o2);                                                   \
    OUT[3] = MAGC(a1 - t1, a3 - t2);                                          \
  }
#define CPLXCOL(SR, SI, OUT)                                                  \
  {                                                                           \
    float t0r = rr[0][SR] + rr[4][SR], t0i = rr[0][SI] + rr[4][SI];           \
    float t1r = rr[0][SR] - rr[4][SR], t1i = rr[0][SI] - rr[4][SI];           \
    float t2r = rr[2][SR] + rr[6][SR], t2i = rr[2][SI] + rr[6][SI];           \
    float t3r = rr[2][SR] - rr[6][SR], t3i = rr[2][SI] - rr[6][SI];           \
    float E0r = t0r + t2r, E0i = t0i + t2i, E2r = t0r - t2r, E2i = t0i - t2i; \
    float E1r = t1r + t3i, E1i = t1i - t3r, E3r = t1r - t3i, E3i = t1i + t3r; \
    float u0r = rr[1][SR] + rr[5][SR], u0i = rr[1][SI] + rr[5][SI];           \
    float u1r = rr[1][SR] - rr[5][SR], u1i = rr[1][SI] - rr[5][SI];           \
    float u2r = rr[3][SR] + rr[7][SR], u2i = rr[3][SI] + rr[7][SI];           \
    float u3r = rr[3][SR] - rr[7][SR], u3i = rr[3][SI] - rr[7][SI];           \
    float O0r = u0r + u2r, O0i = u0i + u2i, O2r = u0r - u2r, O2i = u0i - u2i; \
    float O1r = u1r + u3i, O1i = u1i - u3r, O3r = u1r - u3i, O3i = u1i + u3r; \
    float W1r = S8 * (O1r + O1i), W1i = S8 * (O1i - O1r);                     \
    float W2r = O2i, W2i = -O2r;                                              \
    float W3r = S8 * (O3i - O3r), W3i = -S8 * (O3r + O3i);                    \
    OUT[0] = MAGC(E0r + O0r, E0i + O0i); OUT[4] = MAGC(E0r - O0r, E0i - O0i); \
    OUT[1] = MAGC(E1r + W1r, E1i + W1i); OUT[5] = MAGC(E1r - W1r, E1i - W1i); \
    OUT[2] = MAGC(E2r + W2r, E2i + W2i); OUT[6] = MAGC(E2r - W2r, E2i - W2i); \
    OUT[3] = MAGC(E3r + W3r, E3i + W3i); OUT[7] = MAGC(E3r - W3r, E3i - W3i); \
  }
    REALCOL(0, mg0)
    REALCOL(1, mg4)
    CPLXCOL(2, 3, mg1)
    CPLXCOL(4, 5, mg2)
    CPLXCOL(6, 7, mg3)
    // hermitian expand + fftshift, packed bf16x8 into G A-fragment layout
    const int pb8 = p * 8, p7 = p & 7;
#pragma unroll
    for (int up = 0; up < 8; ++up) {
      union { unsigned short h[8]; short8 v; } pk;
#pragma unroll
      for (int vp = 0; vp < 8; ++vp) {
        const int u = (up + 4) & 7, vx = (vp + 4) & 7;
        float m;
        if (vx == 0)      m = mg0[(u <= 4) ? u : (8 - u)];
        else if (vx == 4) m = mg4[(u <= 4) ? u : (8 - u)];
        else if (vx == 1) m = mg1[u];
        else if (vx == 2) m = mg2[u];
        else if (vx == 3) m = mg3[u];
        else { const int uu = (8 - u) & 7;
               m = (vx == 5) ? mg3[uu] : (vx == 6) ? mg2[uu] : mg1[uu]; }
        pk.h[vp] = f2bf(m);
      }
      ldsX[pb8 + (up ^ p7)] = pk.v;
    }
  }
  __syncthreads();

  // ---- polar sampling + radial sum as MFMA: psum = mag(256x64) * G(64x16) ----
  {
    short8 gf0 = wsV[384 + lane];
    short8 gf1 = wsV[448 + lane];
    f32x4 ag[4];
#pragma unroll
    for (int pt = 0; pt < 4; ++pt) {
      int prow = (wave * 4 + pt) * 16 + (lane & 15);
      int p7 = prow & 7, pb = prow * 8;
      short8 a0 = ldsX[pb + (kcA ^ p7)];
      short8 a1 = ldsX[pb + ((kcA + 4) ^ p7)];
      f32x4 zf = (f32x4){0.f, 0.f, 0.f, 0.f};
      zf = __builtin_amdgcn_mfma_f32_16x16x32_bf16(a0, gf0, zf, 0, 0, 0);
      zf = __builtin_amdgcn_mfma_f32_16x16x32_bf16(a1, gf1, zf, 0, 0, 0);
      ag[pt] = zf;
    }
    float s0 = ag[0][0] + ag[0][1] + ag[0][2] + ag[0][3] +
               ag[1][0] + ag[1][1] + ag[1][2] + ag[1][3];
    float s1 = ag[2][0] + ag[2][1] + ag[2][2] + ag[2][3] +
               ag[3][0] + ag[3][1] + ag[3][2] + ag[3][3];
    s0 += __shfl_xor(s0, 16); s0 += __shfl_xor(s0, 32);
    s1 += __shfl_xor(s1, 16); s1 += __shfl_xor(s1, 32);
    float l0 = s0 * (1.0f / 256.0f), l1 = s1 * (1.0f / 256.0f);
    float m0 = l0, m1 = l1;
#pragma unroll
    for (int mk = 1; mk < 16; mk <<= 1) {
      m0 = fmaxf(m0, __shfl_xor(m0, mk));
      m1 = fmaxf(m1, __shfl_xor(m1, mk));
    }
    float e0 = expf(l0 - m0), e1 = expf(l1 - m1);
    float ss0 = e0, ss1 = e1;
#pragma unroll
    for (int mk = 1; mk < 16; mk <<= 1) {
      ss0 += __shfl_xor(ss0, mk);
      ss1 += __shfl_xor(ss1, mk);
    }
    float d0 = e0 / ss0, d1 = e1 / ss1;
    float h0 = -d0 * logf(fmaxf(d0, 1e-8f));
    float h1 = -d1 * logf(fmaxf(d1, 1e-8f));
#pragma unroll
    for (int mk = 1; mk < 16; mk <<= 1) {
      h0 += __shfl_xor(h0, mk);
      h1 += __shfl_xor(h1, mk);
    }
    float c0 = fminf(fmaxf(1.f - h0 * (1.0f / 2.7725887222397811f), 0.f), 1.f);
    float c1 = fminf(fmaxf(1.f - h1 * (1.0f / 2.7725887222397811f), 0.f), 1.f);
    if (lane < 16) {
      obuf[wave * 32 + lane] = d0;
      obuf[wave * 32 + 16 + lane] = d1;
    }
    if (lane == 0) {
      obuf[128 + wave * 2] = c0;
      obuf[128 + wave * 2 + 1] = c1;
    }
  }
  __syncthreads();

  if (tid < 128) {
    int t = tid >> 3, win = tid & 7;
    int wx = wxg * 8 + win;
    out[((size_t)(b * NT + t) * HG + hy) * WG + wx] = obuf[win * 16 + t];
  } else if (tid < 136) {
    int win = tid - 128;
    int wx = wxg * 8 + win;
    out[(size_t)NB * NT * HG * WG + ((size_t)b * HG + hy) * WG + wx] =
        obuf[128 + win];
  }
}

extern "C" void kernel_launch(void* const* d_in, const int* in_sizes, int n_in,
                              void* d_out, int out_size, void* d_ws,
                              size_t ws_size, hipStream_t stream) {
  (void)in_sizes; (void)n_in; (void)ws_size; (void)out_size;
  const float* x = (const float*)d_in[0];
  const float* Wp = (const float*)d_in[1];
  const float* bp = (const float*)d_in[2];
  unsigned short* ws = (unsigned short*)d_ws;
  float* out = (float*)d_out;
  lpp_setup<<<8, 256, 0, stream>>>(Wp, ws);
  lpp_main<<<NB * HG * 6, 256, 0, stream>>>(x, bp, ws, out);
}